// Round 1
// 258.525 us; speedup vs baseline: 1.0012x; 1.0012x over previous
//
#include <hip/hip_runtime.h>

// ---------------- bf16 helpers (raw ushort storage; RNE convert) ----------------
typedef unsigned short ushort_t;
typedef unsigned int uint_t;

__device__ __forceinline__ float bf2f(ushort_t u) {
    union { float f; uint_t i; } c; c.i = ((uint_t)u) << 16; return c.f;
}
__device__ __forceinline__ ushort_t f2bf(float f) {
    union { float f; uint_t i; } c; c.f = f;
    uint_t i = c.i;
    return (ushort_t)((i + 0x7fffu + ((i >> 16) & 1u)) >> 16);   // RNE
}

typedef __attribute__((ext_vector_type(8))) short short8;
typedef __attribute__((ext_vector_type(4))) float float4v;

// ---------------- problem constants ----------------
#define BATCH 16384
#define NV    100000
#define K1    480     // [0..415] emb | [416..431] c_hi | [432..447] c_lo | [448..463] c_hi | [464..479] 0
#define K2    416     // h1 400 + 16 zero pad
#define S1    15      // K1/32
#define S2    13      // K2/32
#define ROWS  32      // batch rows per block: 512 blocks -> 2 blocks/CU, phase A/B overlap across blocks
#define WPB   8       // waves per block (512 thr -> 4 waves/SIMD at 2 blocks/CU)
#define SA    488     // smA row stride (elems); 976 B -> row skew -> <=2-way (free)
#define SH    456     // smH row stride; 912 B -> <=2-way (free)

// fragment-ordered weights: frag(t,s) = 64 lanes x 16B contiguous (1 KB)
#define OFF_W1F 0u           // 25*15*512*2 = 384000 B
#define OFF_W2F 384000u      // 25*13*512*2 = 332800 B  (total ~700 KB ws)

// ================= K0: fragment-parallel weight prep =================
// One 64-lane wave builds one 1 KB fragment: lane writes one coalesced short8;
// the 16 lanes of each n-group share every 64 B read granule of W1/W2.
// 700 frags x 64 lanes = 44800 threads = 175 blocks x 256.
__global__ void prep_weights(const float* __restrict__ W1, const float* __restrict__ W2,
                             ushort_t* __restrict__ W1f, ushort_t* __restrict__ W2f) {
    int gid  = blockIdx.x * 256 + threadIdx.x;
    int frag = gid >> 6, lane = gid & 63;
    int q = lane >> 4, mr = lane & 15;
    short8 o;
    if (frag < 25 * S1) {                       // W1 fragment
        int t = frag / S1, s = frag % S1;
        int n = t * 16 + mr;
        #pragma unroll
        for (int j = 0; j < 8; ++j) {
            int k = s * 32 + q * 8 + j;
            float v = 0.f;
            if (k < 416) {
                v = W1[(size_t)(13 + k) * 400 + n];                  // emb rows
            } else if (k < 448) {
                int j2 = k - (k < 432 ? 416 : 432);
                if (j2 < 13) v = W1[(size_t)j2 * 400 + n];           // w_hi (twice)
            } else if (k < 464) {
                int j2 = k - 448;
                if (j2 < 13) {
                    float wv = W1[(size_t)j2 * 400 + n];
                    v = wv - bf2f(f2bf(wv));                          // w_lo
                }
            }
            o[j] = (short)f2bf(v);
        }
        *(short8*)&W1f[(size_t)(frag * 64 + lane) * 8] = o;
    } else if (frag < 25 * (S1 + S2)) {         // W2 fragment
        int f2i = frag - 25 * S1;
        int t = f2i / S2, s = f2i % S2;
        int n = t * 16 + mr;
        #pragma unroll
        for (int j = 0; j < 8; ++j) {
            int k = s * 32 + q * 8 + j;
            float v = (k < 400) ? W2[(size_t)k * 400 + n] : 0.f;
            o[j] = (short)f2bf(v);
        }
        *(short8*)&W2f[(size_t)(f2i * 64 + lane) * 8] = o;
    }
}

// ================= K1: fully fused DeepFM =================
// 512 blocks x 512 threads; block owns 32 batch rows; ragged N-split {4,3x7}.
// 2 blocks/CU: one block's gather latency hides under the other's GEMM.
__global__ __launch_bounds__(512, 4) void fused_deepfm(
    const float* __restrict__ cont, const int* __restrict__ cat,
    const float* __restrict__ w_cont, const float* __restrict__ b_cont,
    const float* __restrict__ t_first, const float* __restrict__ t_emb,
    const ushort_t* __restrict__ W1f, const float* __restrict__ b1,
    const ushort_t* __restrict__ W2f, const float* __restrict__ b2,
    const float* __restrict__ Wout, const float* __restrict__ bout,
    float* __restrict__ out)
{
    __shared__ __align__(16) ushort_t smA[ROWS * SA];   // 31232 B; aliased by smH (stride SH)
    __shared__ float smFM[ROWS];                        // 128 B
    __shared__ float smP[WPB * ROWS];                   // 1024 B  (total ~32.4 KB -> 2 blocks/CU)

    int tid  = threadIdx.x;
    int wv   = tid >> 6, lane = tid & 63;
    int quad = lane >> 4, mrow = lane & 15;
    int b0   = blockIdx.x * ROWS;
    ushort_t* smH = smA;
    const int ntiles = (wv == 0) ? 4 : 3;          // 4+7*3 = 25 real tiles
    const int tbase  = (wv == 0) ? 0 : (1 + 3 * wv);

    // ---- Phase A: gather + FM (fp32 exact) + build dnn tile in LDS ----
    {
        int r4 = lane >> 4, fs = (lane >> 2) & 3, sub = lane & 3, l16 = lane & 15;
        int R  = wv * 4 + r4;                      // 8 waves x 4 rows = 32
        int gR = b0 + R;
        // hoist ALL loads (indices, 7x emb float4, 7x t_first, cont) for max MLP
        int idxv[7];
        #pragma unroll
        for (int it = 0; it < 7; ++it) {
            int f = it * 4 + fs;
            idxv[it] = (f < 26) ? cat[gR * 26 + f] : 0;
        }
        float4 ev[7];
        float  tfv[7];
        float  cv = (l16 < 13) ? cont[gR * 13 + l16] : 0.f;
        #pragma unroll
        for (int it = 0; it < 7; ++it) {
            int f = it * 4 + fs;
            if (f < 26) {
                size_t base = (size_t)f * NV + idxv[it];
                ev[it]  = *(const float4*)(t_emb + (base << 4) + sub * 4);
                tfv[it] = t_first[base];   // same addr across sub lanes -> merged
            }
        }
        float sj0 = 0, sj1 = 0, sj2 = 0, sj3 = 0, ssq = 0, pacc = 0;
        #pragma unroll
        for (int it = 0; it < 7; ++it) {
            int f = it * 4 + fs;
            if (f < 26) {
                float4 v = ev[it];
                sj0 += v.x; sj1 += v.y; sj2 += v.z; sj3 += v.w;
                ssq += v.x * v.x + v.y * v.y + v.z * v.z + v.w * v.w;
                uint_t lo = (uint_t)f2bf(v.x) | ((uint_t)f2bf(v.y) << 16);
                uint_t hi = (uint_t)f2bf(v.z) | ((uint_t)f2bf(v.w) << 16);
                uint2 pk = make_uint2(lo, hi);
                *(uint2*)&smA[R * SA + f * 16 + sub * 4] = pk;   // 8B-aligned
                if (sub == 0) pacc += tfv[it];
            }
        }
        float c = cv;
        if (l16 < 13) pacc += c * w_cont[l16];
        ushort_t ch = f2bf(c);
        float cl = c - bf2f(ch);
        smA[R * SA + 416 + l16] = ch;
        smA[R * SA + 432 + l16] = f2bf(cl);
        smA[R * SA + 448 + l16] = ch;
        smA[R * SA + 464 + l16] = 0;
        sj0 += __shfl_xor(sj0, 4); sj0 += __shfl_xor(sj0, 8);
        sj1 += __shfl_xor(sj1, 4); sj1 += __shfl_xor(sj1, 8);
        sj2 += __shfl_xor(sj2, 4); sj2 += __shfl_xor(sj2, 8);
        sj3 += __shfl_xor(sj3, 4); sj3 += __shfl_xor(sj3, 8);
        float q = pacc - 0.5f * ssq;
        if (fs == 0) q += 0.5f * (sj0 * sj0 + sj1 * sj1 + sj2 * sj2 + sj3 * sj3);
        q += __shfl_xor(q, 1); q += __shfl_xor(q, 2);
        q += __shfl_xor(q, 4); q += __shfl_xor(q, 8);
        if (l16 == 0) smFM[R] = q + b_cont[0];
    }
    __syncthreads();

    // ---- Phase B: GEMM1, fragment-ordered B streamed L2->regs, A from LDS ----
    {
        const ushort_t* Bb = W1f + (size_t)(tbase * S1) * 512 + lane * 8;
        short8 bcur[4], bnxt[4];
        #pragma unroll
        for (int ni = 0; ni < 4; ++ni)
            if (ni < ntiles) bcur[ni] = *(const short8*)(Bb + (size_t)(ni * S1) * 512);
        float4v acc[2][4] = {};
        #pragma unroll 1
        for (int s = 0; s < S1; ++s) {
            if (s < S1 - 1) {
                #pragma unroll
                for (int ni = 0; ni < 4; ++ni)
                    if (ni < ntiles) bnxt[ni] = *(const short8*)(Bb + (size_t)(ni * S1 + s + 1) * 512);
            }
            short8 af[2];
            #pragma unroll
            for (int mt = 0; mt < 2; ++mt)
                af[mt] = *(const short8*)&smA[(mt * 16 + mrow) * SA + s * 32 + quad * 8];
            #pragma unroll
            for (int ni = 0; ni < 4; ++ni)
                if (ni < ntiles)
                    #pragma unroll
                    for (int mt = 0; mt < 2; ++mt)
                        acc[mt][ni] = __builtin_amdgcn_mfma_f32_16x16x32_bf16(af[mt], bcur[ni], acc[mt][ni], 0, 0, 0);
            #pragma unroll
            for (int ni = 0; ni < 4; ++ni) bcur[ni] = bnxt[ni];
        }
        __syncthreads();   // drain smA frag reads before smH overwrites the region
        #pragma unroll
        for (int ni = 0; ni < 4; ++ni)
            if (ni < ntiles) {
                int col = (tbase + ni) * 16 + mrow;     // < 400 by construction
                float bv = b1[col];
                #pragma unroll
                for (int mt = 0; mt < 2; ++mt)
                    #pragma unroll
                    for (int r = 0; r < 4; ++r) {
                        int row = mt * 16 + quad * 4 + r;
                        smH[row * SH + col] = f2bf(fmaxf(acc[mt][ni][r] + bv, 0.f));
                    }
            }
        if (wv == 7) {   // zero pad cols 400..415 across all 32 rows
            #pragma unroll
            for (int r = 0; r < 8; ++r)
                smH[(r * 4 + quad) * SH + 400 + mrow] = 0;
        }
    }
    __syncthreads();

    // ---- Phase C: GEMM2 + fused W_out dot ----
    {
        const ushort_t* Bb = W2f + (size_t)(tbase * S2) * 512 + lane * 8;
        short8 bcur[4], bnxt[4];
        #pragma unroll
        for (int ni = 0; ni < 4; ++ni)
            if (ni < ntiles) bcur[ni] = *(const short8*)(Bb + (size_t)(ni * S2) * 512);
        float4v acc[2][4] = {};
        #pragma unroll 1
        for (int s = 0; s < S2; ++s) {
            if (s < S2 - 1) {
                #pragma unroll
                for (int ni = 0; ni < 4; ++ni)
                    if (ni < ntiles) bnxt[ni] = *(const short8*)(Bb + (size_t)(ni * S2 + s + 1) * 512);
            }
            short8 af[2];
            #pragma unroll
            for (int mt = 0; mt < 2; ++mt)
                af[mt] = *(const short8*)&smH[(mt * 16 + mrow) * SH + s * 32 + quad * 8];
            #pragma unroll
            for (int ni = 0; ni < 4; ++ni)
                if (ni < ntiles)
                    #pragma unroll
                    for (int mt = 0; mt < 2; ++mt)
                        acc[mt][ni] = __builtin_amdgcn_mfma_f32_16x16x32_bf16(af[mt], bcur[ni], acc[mt][ni], 0, 0, 0);
            #pragma unroll
            for (int ni = 0; ni < 4; ++ni) bcur[ni] = bnxt[ni];
        }
        float p[2][4] = {};
        #pragma unroll
        for (int ni = 0; ni < 4; ++ni)
            if (ni < ntiles) {
                int col = (tbase + ni) * 16 + mrow;     // < 400
                float bv = b2[col], wvv = Wout[1 + col];
                #pragma unroll
                for (int mt = 0; mt < 2; ++mt)
                    #pragma unroll
                    for (int r = 0; r < 4; ++r)
                        p[mt][r] += fmaxf(acc[mt][ni][r] + bv, 0.f) * wvv;
            }
        #pragma unroll
        for (int mt = 0; mt < 2; ++mt)
            #pragma unroll
            for (int r = 0; r < 4; ++r) {
                float v = p[mt][r];
                v += __shfl_xor(v, 1); v += __shfl_xor(v, 2);
                v += __shfl_xor(v, 4); v += __shfl_xor(v, 8);
                p[mt][r] = v;
            }
        if (mrow == 0) {
            #pragma unroll
            for (int mt = 0; mt < 2; ++mt)
                #pragma unroll
                for (int r = 0; r < 4; ++r)
                    smP[wv * ROWS + mt * 16 + quad * 4 + r] = p[mt][r];
        }
    }
    __syncthreads();

    // ---- finalize: combine 8 wave-partials + FM branch ----
    if (tid < ROWS) {
        float o = 0.f;
        #pragma unroll
        for (int w = 0; w < WPB; ++w) o += smP[w * ROWS + tid];
        out[b0 + tid] = o + smFM[tid] * Wout[0] + bout[0];
    }
}

// ================= launch =================
extern "C" void kernel_launch(void* const* d_in, const int* in_sizes, int n_in,
                              void* d_out, int out_size, void* d_ws, size_t ws_size,
                              hipStream_t stream) {
    const float* cont    = (const float*)d_in[0];
    const int*   cat     = (const int*)d_in[1];
    const float* w_cont  = (const float*)d_in[2];
    const float* b_cont  = (const float*)d_in[3];
    const float* t_first = (const float*)d_in[4];
    const float* t_emb   = (const float*)d_in[5];
    const float* W1      = (const float*)d_in[6];
    const float* b1      = (const float*)d_in[7];
    const float* W2      = (const float*)d_in[8];
    const float* b2      = (const float*)d_in[9];
    const float* Wout    = (const float*)d_in[10];
    const float* bout    = (const float*)d_in[11];
    float* out = (float*)d_out;

    char* w = (char*)d_ws;
    ushort_t* W1f = (ushort_t*)(w + OFF_W1F);
    ushort_t* W2f = (ushort_t*)(w + OFF_W2F);

    // K0: fragment-parallel weight prep (700 frags x 64 lanes = 175 blocks)
    prep_weights<<<175, 256, 0, stream>>>(W1, W2, W1f, W2f);
    // K1: fully fused forward, 32 rows/block, 8 waves, 2 blocks/CU
    fused_deepfm<<<BATCH / ROWS, 512, 0, stream>>>(cont, cat, w_cont, b_cont,
                                                   t_first, t_emb, W1f, b1, W2f, b2,
                                                   Wout, bout, out);
}